// Round 1
// baseline (1673.164 us; speedup 1.0000x reference)
//
#include <hip/hip_runtime.h>

#define DIMN 1024
#define NH 16
#define HD 64
#define SEQ 2048
#define BATCH 2
#define BHN (BATCH*NH)        // 32
#define MROWS (BATCH*SEQ)     // 4096
#define KKEEP 409
#define SCALEF 0.125f

// ---------------- K1: QKV projection GEMM (y = x @ W^T + b) ----------------
// x: [4096, 1024] row-major. W: [1024(e), 1024(d)] row-major.
// dst layout: [B*H, S, 64]
__global__ __launch_bounds__(256) void qkv_gemm(
    const float* __restrict__ x,
    const float* __restrict__ wq, const float* __restrict__ bq,
    const float* __restrict__ wk, const float* __restrict__ bk,
    const float* __restrict__ wv, const float* __restrict__ bv,
    float* __restrict__ q, float* __restrict__ k, float* __restrict__ v)
{
    const float* w; const float* bias; float* dst;
    if (blockIdx.z == 0)      { w = wq; bias = bq; dst = q; }
    else if (blockIdx.z == 1) { w = wk; bias = bk; dst = k; }
    else                      { w = wv; bias = bv; dst = v; }

    __shared__ float xs[64][17];
    __shared__ float wsh[64][17];
    const int t = threadIdx.x;
    const int tx = t & 15, ty = t >> 4;
    const int m0 = blockIdx.x * 64;
    const int e0 = blockIdx.y * 64;     // head = blockIdx.y
    float acc[4][4] = {};

    for (int kc = 0; kc < DIMN; kc += 16) {
        #pragma unroll
        for (int i = 0; i < 4; ++i) {
            int lin = t + 256 * i;
            int r = lin >> 4, c = lin & 15;
            xs[r][c]  = x[(size_t)(m0 + r) * DIMN + kc + c];
            wsh[r][c] = w[(size_t)(e0 + r) * DIMN + kc + c];
        }
        __syncthreads();
        #pragma unroll
        for (int kk = 0; kk < 16; ++kk) {
            float a[4], b[4];
            #pragma unroll
            for (int i = 0; i < 4; ++i) a[i] = xs[ty * 4 + i][kk];
            #pragma unroll
            for (int j = 0; j < 4; ++j) b[j] = wsh[tx * 4 + j][kk];
            #pragma unroll
            for (int i = 0; i < 4; ++i)
                #pragma unroll
                for (int j = 0; j < 4; ++j)
                    acc[i][j] += a[i] * b[j];
        }
        __syncthreads();
    }

    const int h = blockIdx.y;
    #pragma unroll
    for (int i = 0; i < 4; ++i) {
        int m = m0 + ty * 4 + i;
        int b = m >> 11, s = m & 2047;
        #pragma unroll
        for (int j = 0; j < 4; ++j) {
            int d = tx * 4 + j;
            dst[((size_t)(b * NH + h) * SEQ + s) * HD + d] = acc[i][j] + bias[e0 + d];
        }
    }
}

// ---------------- K2: scores = SCALE * q @ k^T, per head --------------------
__global__ __launch_bounds__(256) void scores_kernel(
    const float* __restrict__ q, const float* __restrict__ k,
    float* __restrict__ attn)
{
    __shared__ float qs[64][65];
    __shared__ float ks[64][65];
    const int t = threadIdx.x;
    const int tx = t & 15, ty = t >> 4;
    const int bh = blockIdx.z;
    const int i0 = blockIdx.x * 64, j0 = blockIdx.y * 64;
    const float* qp = q + (size_t)(bh * SEQ + i0) * HD;
    const float* kp = k + (size_t)(bh * SEQ + j0) * HD;

    #pragma unroll
    for (int r = 0; r < 4; ++r) {
        int lin = t + 256 * r;            // float4 index; row*16 + c4
        int row = lin >> 4, c4 = lin & 15;
        float4 qv = ((const float4*)qp)[lin];
        float4 kv = ((const float4*)kp)[lin];
        qs[row][c4 * 4 + 0] = qv.x; qs[row][c4 * 4 + 1] = qv.y;
        qs[row][c4 * 4 + 2] = qv.z; qs[row][c4 * 4 + 3] = qv.w;
        ks[row][c4 * 4 + 0] = kv.x; ks[row][c4 * 4 + 1] = kv.y;
        ks[row][c4 * 4 + 2] = kv.z; ks[row][c4 * 4 + 3] = kv.w;
    }
    __syncthreads();

    float acc[4][4] = {};
    #pragma unroll 8
    for (int d = 0; d < HD; ++d) {
        float a[4], b[4];
        #pragma unroll
        for (int i = 0; i < 4; ++i) a[i] = qs[ty * 4 + i][d];
        #pragma unroll
        for (int j = 0; j < 4; ++j) b[j] = ks[tx * 4 + j][d];
        #pragma unroll
        for (int i = 0; i < 4; ++i)
            #pragma unroll
            for (int j = 0; j < 4; ++j)
                acc[i][j] += a[i] * b[j];
    }

    #pragma unroll
    for (int i = 0; i < 4; ++i) {
        size_t rowbase = ((size_t)bh * SEQ + i0 + ty * 4 + i) * SEQ;
        #pragma unroll
        for (int j = 0; j < 4; ++j)
            attn[rowbase + j0 + tx * 4 + j] = acc[i][j] * SCALEF;
    }
}

// ---------------- K3: per-row exact top-409 select + softmax (in place) -----
// One wave (64 lanes) per row; 32 values per lane in registers.
__global__ __launch_bounds__(256) void select_softmax(float* __restrict__ attn)
{
    const int wave = threadIdx.x >> 6;
    const int lane = threadIdx.x & 63;
    const size_t row = (size_t)blockIdx.x * 4 + wave;   // < 65536
    float* rp = attn + row * SEQ;

    float vals[32];
    unsigned u[32];
    #pragma unroll
    for (int j = 0; j < 32; ++j) {
        float f = rp[lane + 64 * j];
        vals[j] = f;
        unsigned fu = __float_as_uint(f);
        u[j] = (fu & 0x80000000u) ? ~fu : (fu | 0x80000000u);
    }

    // binary search: largest t with count(u >= t) >= KKEEP
    unsigned cur = 0u;
    for (int bit = 31; bit >= 0; --bit) {
        unsigned cand = cur | (1u << bit);
        int c = 0;
        #pragma unroll
        for (int j = 0; j < 32; ++j) c += (u[j] >= cand) ? 1 : 0;
        #pragma unroll
        for (int off = 32; off > 0; off >>= 1) c += __shfl_xor(c, off);
        if (c >= KKEEP) cur = cand;
    }

    // row max (always a kept element)
    float m = -3.0e38f;
    #pragma unroll
    for (int j = 0; j < 32; ++j) m = fmaxf(m, vals[j]);
    #pragma unroll
    for (int off = 32; off > 0; off >>= 1) m = fmaxf(m, __shfl_xor(m, off));

    // exp over kept, denom, normalize, write back
    float denom = 0.f;
    #pragma unroll
    for (int j = 0; j < 32; ++j) {
        float e = (u[j] >= cur) ? __expf(vals[j] - m) : 0.f;
        vals[j] = e;
        denom += e;
    }
    #pragma unroll
    for (int off = 32; off > 0; off >>= 1) denom += __shfl_xor(denom, off);
    float inv = 1.0f / denom;
    #pragma unroll
    for (int j = 0; j < 32; ++j) rp[lane + 64 * j] = vals[j] * inv;
}

// ---------------- K4: ctx = attn @ v, per head ------------------------------
__global__ __launch_bounds__(256) void pv_gemm(
    const float* __restrict__ attn, const float* __restrict__ v,
    float* __restrict__ ctx)
{
    __shared__ float as_[64][65];
    __shared__ float vs_[64][65];
    const int t = threadIdx.x;
    const int tx = t & 15, ty = t >> 4;
    const int bh = blockIdx.z;
    const int i0 = blockIdx.x * 64;
    const float* ap = attn + (size_t)(bh * SEQ + i0) * SEQ;
    const float* vp = v + (size_t)bh * SEQ * HD;
    float acc[4][4] = {};

    for (int jc = 0; jc < SEQ; jc += 64) {
        #pragma unroll
        for (int r = 0; r < 4; ++r) {
            int lin = t + 256 * r;
            int row = lin >> 4, c4 = lin & 15;
            float4 av = *(const float4*)(ap + (size_t)row * SEQ + jc + c4 * 4);
            float4 vv = *(const float4*)(vp + (size_t)(jc + row) * HD + c4 * 4);
            as_[row][c4 * 4 + 0] = av.x; as_[row][c4 * 4 + 1] = av.y;
            as_[row][c4 * 4 + 2] = av.z; as_[row][c4 * 4 + 3] = av.w;
            vs_[row][c4 * 4 + 0] = vv.x; vs_[row][c4 * 4 + 1] = vv.y;
            vs_[row][c4 * 4 + 2] = vv.z; vs_[row][c4 * 4 + 3] = vv.w;
        }
        __syncthreads();
        #pragma unroll 8
        for (int jj = 0; jj < 64; ++jj) {
            float a[4], b[4];
            #pragma unroll
            for (int i = 0; i < 4; ++i) a[i] = as_[ty * 4 + i][jj];
            #pragma unroll
            for (int j = 0; j < 4; ++j) b[j] = vs_[jj][tx * 4 + j];
            #pragma unroll
            for (int i = 0; i < 4; ++i)
                #pragma unroll
                for (int j = 0; j < 4; ++j)
                    acc[i][j] += a[i] * b[j];
        }
        __syncthreads();
    }

    #pragma unroll
    for (int i = 0; i < 4; ++i)
        #pragma unroll
        for (int j = 0; j < 4; ++j)
            ctx[((size_t)bh * SEQ + i0 + ty * 4 + i) * HD + tx * 4 + j] = acc[i][j];
}

// ---------------- K5: out = ctx(reshaped) @ wo^T + bo ----------------------
__global__ __launch_bounds__(256) void out_gemm(
    const float* __restrict__ ctx, const float* __restrict__ wo,
    const float* __restrict__ bo, float* __restrict__ out)
{
    __shared__ float as_[64][17];
    __shared__ float wsh[64][17];
    const int t = threadIdx.x;
    const int tx = t & 15, ty = t >> 4;
    const int m0 = blockIdx.x * 64;
    const int e0 = blockIdx.y * 64;
    float acc[4][4] = {};

    for (int kc = 0; kc < DIMN; kc += 16) {
        int h0 = kc >> 6;
        int d0 = kc & 63;
        #pragma unroll
        for (int i = 0; i < 4; ++i) {
            int lin = t + 256 * i;
            int r = lin >> 4, c = lin & 15;
            int m = m0 + r;
            int b = m >> 11, s = m & 2047;
            as_[r][c] = ctx[((size_t)(b * NH + h0) * SEQ + s) * HD + d0 + c];
            wsh[r][c] = wo[(size_t)(e0 + r) * DIMN + kc + c];
        }
        __syncthreads();
        #pragma unroll
        for (int kk = 0; kk < 16; ++kk) {
            float a[4], b[4];
            #pragma unroll
            for (int i = 0; i < 4; ++i) a[i] = as_[ty * 4 + i][kk];
            #pragma unroll
            for (int j = 0; j < 4; ++j) b[j] = wsh[tx * 4 + j][kk];
            #pragma unroll
            for (int i = 0; i < 4; ++i)
                #pragma unroll
                for (int j = 0; j < 4; ++j)
                    acc[i][j] += a[i] * b[j];
        }
        __syncthreads();
    }

    #pragma unroll
    for (int i = 0; i < 4; ++i) {
        int m = m0 + ty * 4 + i;
        #pragma unroll
        for (int j = 0; j < 4; ++j)
            out[(size_t)m * DIMN + e0 + tx * 4 + j] = acc[i][j] + bo[e0 + tx * 4 + j];
    }
}

extern "C" void kernel_launch(void* const* d_in, const int* in_sizes, int n_in,
                              void* d_out, int out_size, void* d_ws, size_t ws_size,
                              hipStream_t stream) {
    const float* x  = (const float*)d_in[0];
    const float* wq = (const float*)d_in[1];
    const float* bq = (const float*)d_in[2];
    const float* wk = (const float*)d_in[3];
    const float* bk = (const float*)d_in[4];
    const float* wv = (const float*)d_in[5];
    const float* bv = (const float*)d_in[6];
    const float* wo = (const float*)d_in[7];
    const float* bo = (const float*)d_in[8];

    float* out  = (float*)d_out;
    float* attn = out + (size_t)BATCH * SEQ * DIMN;   // second tuple output

    const size_t qkv_elems = (size_t)BHN * SEQ * HD;  // 4,194,304
    float* q   = (float*)d_ws;
    float* k   = q + qkv_elems;
    float* v   = k + qkv_elems;
    float* ctx = v + qkv_elems;

    qkv_gemm<<<dim3(MROWS / 64, DIMN / 64, 3), 256, 0, stream>>>(
        x, wq, bq, wk, bk, wv, bv, q, k, v);
    scores_kernel<<<dim3(SEQ / 64, SEQ / 64, BHN), 256, 0, stream>>>(q, k, attn);
    select_softmax<<<dim3(BHN * SEQ / 4), 256, 0, stream>>>(attn);
    pv_gemm<<<dim3(SEQ / 64, 1, BHN), 256, 0, stream>>>(attn, v, ctx);
    out_gemm<<<dim3(MROWS / 64, DIMN / 64), 256, 0, stream>>>(ctx, wo, bo, out);
}

// Round 3
// 1205.429 us; speedup vs baseline: 1.3880x; 1.3880x over previous
//
#include <hip/hip_runtime.h>
#include <hip/hip_bf16.h>

#define DIMN 1024
#define NH 16
#define HD 64
#define SEQ 2048
#define BATCH 2
#define BHN (BATCH*NH)        // 32
#define MROWS (BATCH*SEQ)     // 4096
#define KKEEP 409
#define SCALEF 0.125f

typedef __attribute__((ext_vector_type(8))) short short8;
typedef __attribute__((ext_vector_type(4))) short short4v;
typedef __attribute__((ext_vector_type(4))) float f32x4;

#define MFMA(a,b,c) __builtin_amdgcn_mfma_f32_16x16x32_bf16(a,b,c,0,0,0)

static __device__ __forceinline__ short f2bf(float f) {
    __hip_bfloat16 h = __float2bfloat16(f);
    return *reinterpret_cast<short*>(&h);
}
static __device__ __forceinline__ float bf2f(short s) {
    __hip_bfloat16 h = *reinterpret_cast<__hip_bfloat16*>(&s);
    return __bfloat162float(h);
}
static __device__ __forceinline__ short8 ld8(const short* p) {
    return *reinterpret_cast<const short8*>(p);
}

// ---------------- K0a: fp32 -> (hi, lo) bf16 pair --------------------------
__global__ void conv_hilo(const float* __restrict__ in,
                          short* __restrict__ hi, short* __restrict__ lo, int n) {
    const int n4 = n >> 2;
    for (int i = blockIdx.x * blockDim.x + threadIdx.x; i < n4;
         i += gridDim.x * blockDim.x) {
        float4 v = reinterpret_cast<const float4*>(in)[i];
        short4v h, l;
        #pragma unroll
        for (int j = 0; j < 4; ++j) {
            float f = (&v.x)[j];
            short hb = f2bf(f);
            h[j] = hb;
            l[j] = f2bf(f - bf2f(hb));
        }
        reinterpret_cast<short4v*>(hi)[i] = h;
        reinterpret_cast<short4v*>(lo)[i] = l;
    }
}

// ---------------- K0b: fp32 -> bf16 ----------------------------------------
__global__ void conv_bf16(const float* __restrict__ in, short* __restrict__ out, int n) {
    const int n4 = n >> 2;
    for (int i = blockIdx.x * blockDim.x + threadIdx.x; i < n4;
         i += gridDim.x * blockDim.x) {
        float4 v = reinterpret_cast<const float4*>(in)[i];
        short4v o;
        o[0] = f2bf(v.x); o[1] = f2bf(v.y); o[2] = f2bf(v.z); o[3] = f2bf(v.w);
        reinterpret_cast<short4v*>(out)[i] = o;
    }
}

// ---------------- K1: Q/K projection, hi/lo precision ----------------------
// y = x @ W^T + b with x,W split hi/lo (3-MFMA scheme). Output split hi/lo.
// dst layout: [B*H][S][64]
__global__ __launch_bounds__(256) void qk_mfma(
    const short* __restrict__ xh, const short* __restrict__ xl,
    const short* __restrict__ wqh, const short* __restrict__ wql, const float* __restrict__ bq,
    const short* __restrict__ wkh, const short* __restrict__ wkl, const float* __restrict__ bk,
    short* __restrict__ qhi, short* __restrict__ qlo,
    short* __restrict__ khi, short* __restrict__ klo)
{
    const int z = blockIdx.z;
    const short* wh = z ? wkh : wqh;
    const short* wl = z ? wkl : wql;
    const float* bias = z ? bk : bq;
    short* dhi = z ? khi : qhi;
    short* dlo = z ? klo : qlo;

    const int tid  = threadIdx.x;
    const int wv_  = tid >> 6, lane = tid & 63;
    const int r    = lane & 15, kg = lane >> 4;
    const int m_base = blockIdx.x * 128 + wv_ * 32;
    const int n_base = blockIdx.y * 64;

    f32x4 acc[2][4] = {};

    for (int ks = 0; ks < 32; ++ks) {
        const int k0 = ks * 32 + kg * 8;
        short8 ah0 = ld8(xh + (size_t)(m_base + r) * DIMN + k0);
        short8 al0 = ld8(xl + (size_t)(m_base + r) * DIMN + k0);
        short8 ah1 = ld8(xh + (size_t)(m_base + 16 + r) * DIMN + k0);
        short8 al1 = ld8(xl + (size_t)(m_base + 16 + r) * DIMN + k0);
        #pragma unroll
        for (int nf = 0; nf < 4; ++nf) {
            short8 bh = ld8(wh + (size_t)(n_base + nf * 16 + r) * DIMN + k0);
            short8 bl = ld8(wl + (size_t)(n_base + nf * 16 + r) * DIMN + k0);
            acc[0][nf] = MFMA(ah0, bh, acc[0][nf]);
            acc[0][nf] = MFMA(ah0, bl, acc[0][nf]);
            acc[0][nf] = MFMA(al0, bh, acc[0][nf]);
            acc[1][nf] = MFMA(ah1, bh, acc[1][nf]);
            acc[1][nf] = MFMA(ah1, bl, acc[1][nf]);
            acc[1][nf] = MFMA(al1, bh, acc[1][nf]);
        }
    }

    const int h = blockIdx.y;
    #pragma unroll
    for (int mf = 0; mf < 2; ++mf)
        #pragma unroll
        for (int nf = 0; nf < 4; ++nf)
            #pragma unroll
            for (int i = 0; i < 4; ++i) {
                const int m  = m_base + mf * 16 + kg * 4 + i;
                const int nn = n_base + nf * 16 + r;
                const float val = acc[mf][nf][i] + bias[nn];
                const int b_ = m >> 11, s = m & 2047;
                const size_t idx = (((size_t)(b_ * NH + h)) * SEQ + s) * HD + nf * 16 + r;
                const short hb = f2bf(val);
                dhi[idx] = hb;
                dlo[idx] = f2bf(val - bf2f(hb));
            }
}

// ---------------- K2: V projection (2-MFMA), transposed output -------------
// vt layout: [B*H][64][S]
__global__ __launch_bounds__(256) void v_mfma(
    const short* __restrict__ xh, const short* __restrict__ xl,
    const short* __restrict__ wvb, const float* __restrict__ bv,
    short* __restrict__ vt)
{
    const int tid  = threadIdx.x;
    const int wv_  = tid >> 6, lane = tid & 63;
    const int r    = lane & 15, kg = lane >> 4;
    const int m_base = blockIdx.x * 128 + wv_ * 32;
    const int n_base = blockIdx.y * 64;

    f32x4 acc[2][4] = {};

    for (int ks = 0; ks < 32; ++ks) {
        const int k0 = ks * 32 + kg * 8;
        short8 ah0 = ld8(xh + (size_t)(m_base + r) * DIMN + k0);
        short8 al0 = ld8(xl + (size_t)(m_base + r) * DIMN + k0);
        short8 ah1 = ld8(xh + (size_t)(m_base + 16 + r) * DIMN + k0);
        short8 al1 = ld8(xl + (size_t)(m_base + 16 + r) * DIMN + k0);
        #pragma unroll
        for (int nf = 0; nf < 4; ++nf) {
            short8 b = ld8(wvb + (size_t)(n_base + nf * 16 + r) * DIMN + k0);
            acc[0][nf] = MFMA(ah0, b, acc[0][nf]);
            acc[0][nf] = MFMA(al0, b, acc[0][nf]);
            acc[1][nf] = MFMA(ah1, b, acc[1][nf]);
            acc[1][nf] = MFMA(al1, b, acc[1][nf]);
        }
    }

    const int h = blockIdx.y;
    #pragma unroll
    for (int mf = 0; mf < 2; ++mf)
        #pragma unroll
        for (int nf = 0; nf < 4; ++nf)
            #pragma unroll
            for (int i = 0; i < 4; ++i) {
                const int m  = m_base + mf * 16 + kg * 4 + i;
                const int nn = n_base + nf * 16 + r;
                const float val = acc[mf][nf][i] + bv[nn];
                const int b_ = m >> 11, s = m & 2047;
                vt[(((size_t)(b_ * NH + h)) * HD + nf * 16 + r) * SEQ + s] = f2bf(val);
            }
}

// ---------------- K3: fused scores + exact top-k + softmax + PV ------------
__global__ __launch_bounds__(512) void fused_attn(
    const short* __restrict__ qh, const short* __restrict__ ql,
    const short* __restrict__ kh, const short* __restrict__ kl,
    const short* __restrict__ vtb, float* __restrict__ attn,
    short* __restrict__ ctxb)
{
    __shared__ float S[16][2048];   // fp32 scores, then bf16 P in-place
    __shared__ float CT[16][64];

    const int tid = threadIdx.x;
    const int w   = tid >> 6, lane = tid & 63;
    const int r   = lane & 15, kg = lane >> 4;
    const int bh  = blockIdx.y;
    const int q0  = blockIdx.x * 16;

    // ---- Phase A: S = SCALE * Q K^T, hi/lo 3-MFMA precision ----
    const size_t qoff = ((size_t)bh * SEQ + q0) * HD + r * HD + kg * 8;
    short8 a0h = ld8(qh + qoff),      a0l = ld8(ql + qoff);
    short8 a1h = ld8(qh + qoff + 32), a1l = ld8(ql + qoff + 32);
    for (int jt = w; jt < SEQ / 16; jt += 8) {
        const int j0 = jt * 16;
        const size_t koff = ((size_t)bh * SEQ + j0) * HD + r * HD + kg * 8;
        short8 b0h = ld8(kh + koff),      b0l = ld8(kl + koff);
        short8 b1h = ld8(kh + koff + 32), b1l = ld8(kl + koff + 32);
        f32x4 acc = {0.f, 0.f, 0.f, 0.f};
        acc = MFMA(a0h, b0h, acc);
        acc = MFMA(a0h, b0l, acc);
        acc = MFMA(a0l, b0h, acc);
        acc = MFMA(a1h, b1h, acc);
        acc = MFMA(a1h, b1l, acc);
        acc = MFMA(a1l, b1h, acc);
        #pragma unroll
        for (int i = 0; i < 4; ++i) S[kg * 4 + i][j0 + r] = acc[i] * SCALEF;
    }
    __syncthreads();

    // ---- Phase B: exact 32-bit radix top-k + softmax ----
    for (int rr = 0; rr < 2; ++rr) {
        const int row = w * 2 + rr;
        float vals[32]; unsigned u[32];
        #pragma unroll
        for (int jj = 0; jj < 32; ++jj) vals[jj] = S[row][lane + 64 * jj];
        #pragma unroll
        for (int jj = 0; jj < 32; ++jj) {
            unsigned fu = __float_as_uint(vals[jj]);
            u[jj] = (fu & 0x80000000u) ? ~fu : (fu | 0x80000000u);
        }
        unsigned cur = 0;
        for (int bit = 31; bit >= 0; --bit) {
            const unsigned cand = cur | (1u << bit);
            int c = 0;
            #pragma unroll
            for (int jj = 0; jj < 32; ++jj) c += (u[jj] >= cand) ? 1 : 0;
            #pragma unroll
            for (int off = 32; off; off >>= 1) c += __shfl_xor(c, off);
            if (c >= KKEEP) cur = cand;
        }
        float m = -3.0e38f;
        #pragma unroll
        for (int jj = 0; jj < 32; ++jj) m = fmaxf(m, vals[jj]);
        #pragma unroll
        for (int off = 32; off; off >>= 1) m = fmaxf(m, __shfl_xor(m, off));
        float denom = 0.f;
        #pragma unroll
        for (int jj = 0; jj < 32; ++jj) {
            const float e = (u[jj] >= cur) ? __expf(vals[jj] - m) : 0.f;
            vals[jj] = e; denom += e;
        }
        #pragma unroll
        for (int off = 32; off; off >>= 1) denom += __shfl_xor(denom, off);
        const float inv = 1.0f / denom;

        float* arow = attn + ((size_t)bh * SEQ + q0 + row) * SEQ;
        char* Sb = (char*)S + row * 8192;
        const int swz = (row & 7) << 4;
        #pragma unroll
        for (int jj = 0; jj < 32; ++jj) {
            const float p = vals[jj] * inv;
            arow[lane + 64 * jj] = p;
            *reinterpret_cast<unsigned short*>(Sb + jj * 128 + ((lane * 2) ^ swz)) =
                (unsigned short)f2bf(p);
        }
    }
    __syncthreads();

    // ---- Phase C: ctx = P @ V (P bf16 LDS swizzled, V^T global) ----
    const int c0    = (w & 3) * 16;
    const int khalf = w >> 2;
    f32x4 acc = {0.f, 0.f, 0.f, 0.f};
    const short* vp = vtb + ((size_t)bh * HD + c0 + r) * SEQ + khalf * 1024;
    const char* Sb2 = (const char*)S;
    const int swzr = (r & 7) << 4;
    for (int ks = 0; ks < 32; ++ks) {
        const int kk = khalf * 32 + ks;
        short8 a = *reinterpret_cast<const short8*>(
            Sb2 + r * 8192 + ((kk * 64 + kg * 16) ^ swzr));
        short8 b = ld8(vp + ks * 32 + kg * 8);
        acc = MFMA(a, b, acc);
    }
    if (khalf == 1) {
        #pragma unroll
        for (int i = 0; i < 4; ++i) CT[kg * 4 + i][c0 + r] = acc[i];
    }
    __syncthreads();
    if (khalf == 0) {
        #pragma unroll
        for (int i = 0; i < 4; ++i) {
            const float val = acc[i] + CT[kg * 4 + i][c0 + r];
            ctxb[((size_t)bh * SEQ + q0 + kg * 4 + i) * HD + c0 + r] = f2bf(val);
        }
    }
}

// ---------------- K4: out = ctx @ wo^T + bo (fp32 out) ---------------------
__global__ __launch_bounds__(256) void out_mfma(
    const short* __restrict__ ctxb, const short* __restrict__ wob,
    const float* __restrict__ bo, float* __restrict__ out)
{
    const int tid = threadIdx.x;
    const int w_  = tid >> 6, lane = tid & 63;
    const int r   = lane & 15, kg = lane >> 4;
    const int m_base = blockIdx.x * 128 + w_ * 32;
    const int n_base = blockIdx.y * 64;

    f32x4 acc[2][4] = {};

    for (int ks = 0; ks < 32; ++ks) {
        const int k0 = ks * 32 + kg * 8;
        const int h = k0 >> 6, hd = k0 & 63;
        short8 a[2];
        #pragma unroll
        for (int mf = 0; mf < 2; ++mf) {
            const int m = m_base + mf * 16 + r;
            const int b_ = m >> 11, s = m & 2047;
            a[mf] = ld8(ctxb + (((size_t)(b_ * NH + h)) * SEQ + s) * HD + hd);
        }
        #pragma unroll
        for (int nf = 0; nf < 4; ++nf) {
            short8 b = ld8(wob + (size_t)(n_base + nf * 16 + r) * DIMN + k0);
            acc[0][nf] = MFMA(a[0], b, acc[0][nf]);
            acc[1][nf] = MFMA(a[1], b, acc[1][nf]);
        }
    }

    #pragma unroll
    for (int mf = 0; mf < 2; ++mf)
        #pragma unroll
        for (int nf = 0; nf < 4; ++nf)
            #pragma unroll
            for (int i = 0; i < 4; ++i) {
                const int m  = m_base + mf * 16 + kg * 4 + i;
                const int nn = n_base + nf * 16 + r;
                out[(size_t)m * DIMN + nn] = acc[mf][nf][i] + bo[nn];
            }
}

extern "C" void kernel_launch(void* const* d_in, const int* in_sizes, int n_in,
                              void* d_out, int out_size, void* d_ws, size_t ws_size,
                              hipStream_t stream) {
    const float* x  = (const float*)d_in[0];
    const float* wq = (const float*)d_in[1];
    const float* bq = (const float*)d_in[2];
    const float* wk = (const float*)d_in[3];
    const float* bk = (const float*)d_in[4];
    const float* wv = (const float*)d_in[5];
    const float* bv = (const float*)d_in[6];
    const float* wo = (const float*)d_in[7];
    const float* bo = (const float*)d_in[8];

    float* out  = (float*)d_out;
    float* attn = out + (size_t)MROWS * DIMN;   // 512 MB region, written by fused_attn

    // --- scratch that dies before fused_attn runs: lives in the attn region ---
    short* xhi = (short*)attn;
    short* xlo = xhi + (size_t)MROWS * DIMN;
    short* wqh = xlo + (size_t)MROWS * DIMN;
    short* wql = wqh + (size_t)DIMN * DIMN;
    short* wkh = wql + (size_t)DIMN * DIMN;
    short* wkl = wkh + (size_t)DIMN * DIMN;
    short* wvb = wkl + (size_t)DIMN * DIMN;

    // --- scratch that must survive into/past fused_attn: lives in d_ws ---
    const size_t QKV = (size_t)BHN * SEQ * HD;  // 4,194,304
    short* qhi = (short*)d_ws;
    short* qlo = qhi + QKV;
    short* khi = qlo + QKV;
    short* klo = khi + QKV;
    short* vt  = klo + QKV;
    short* ctx = vt  + QKV;
    short* wob = ctx + QKV;

    conv_hilo<<<1024, 256, 0, stream>>>(x,  xhi, xlo, MROWS * DIMN);
    conv_hilo<<<512,  256, 0, stream>>>(wq, wqh, wql, DIMN * DIMN);
    conv_hilo<<<512,  256, 0, stream>>>(wk, wkh, wkl, DIMN * DIMN);
    conv_bf16<<<512,  256, 0, stream>>>(wv, wvb, DIMN * DIMN);
    conv_bf16<<<512,  256, 0, stream>>>(wo, wob, DIMN * DIMN);

    qk_mfma<<<dim3(MROWS / 128, DIMN / 64, 2), 256, 0, stream>>>(
        xhi, xlo, wqh, wql, bq, wkh, wkl, bk, qhi, qlo, khi, klo);
    v_mfma<<<dim3(MROWS / 128, DIMN / 64), 256, 0, stream>>>(
        xhi, xlo, wvb, bv, vt);

    fused_attn<<<dim3(SEQ / 16, BHN), 512, 0, stream>>>(
        qhi, qlo, khi, klo, vt, attn, ctx);

    out_mfma<<<dim3(MROWS / 128, DIMN / 64), 256, 0, stream>>>(ctx, wob, bo, out);
}

// Round 4
// 1136.296 us; speedup vs baseline: 1.4725x; 1.0608x over previous
//
#include <hip/hip_runtime.h>
#include <hip/hip_bf16.h>

#define DIMN 1024
#define NH 16
#define HD 64
#define SEQ 2048
#define BATCH 2
#define BHN (BATCH*NH)        // 32
#define MROWS (BATCH*SEQ)     // 4096
#define KKEEP 409
#define SCALEF 0.125f

typedef __attribute__((ext_vector_type(8))) short short8;
typedef __attribute__((ext_vector_type(4))) short short4v;
typedef __attribute__((ext_vector_type(4))) float f32x4;

#define MFMA(a,b,c) __builtin_amdgcn_mfma_f32_16x16x32_bf16(a,b,c,0,0,0)

static __device__ __forceinline__ short f2bf(float f) {
    __hip_bfloat16 h = __float2bfloat16(f);
    return *reinterpret_cast<short*>(&h);
}
static __device__ __forceinline__ float bf2f(short s) {
    __hip_bfloat16 h = *reinterpret_cast<__hip_bfloat16*>(&s);
    return __bfloat162float(h);
}
static __device__ __forceinline__ short8 ld8(const short* p) {
    return *reinterpret_cast<const short8*>(p);
}

// ---------------- K0a: fp32 -> (hi, lo) bf16 pair --------------------------
__global__ void conv_hilo(const float* __restrict__ in,
                          short* __restrict__ hi, short* __restrict__ lo, int n) {
    const int n4 = n >> 2;
    for (int i = blockIdx.x * blockDim.x + threadIdx.x; i < n4;
         i += gridDim.x * blockDim.x) {
        float4 v = reinterpret_cast<const float4*>(in)[i];
        short4v h, l;
        #pragma unroll
        for (int j = 0; j < 4; ++j) {
            float f = (&v.x)[j];
            short hb = f2bf(f);
            h[j] = hb;
            l[j] = f2bf(f - bf2f(hb));
        }
        reinterpret_cast<short4v*>(hi)[i] = h;
        reinterpret_cast<short4v*>(lo)[i] = l;
    }
}

// ---------------- K0b: fp32 -> bf16 ----------------------------------------
__global__ void conv_bf16(const float* __restrict__ in, short* __restrict__ out, int n) {
    const int n4 = n >> 2;
    for (int i = blockIdx.x * blockDim.x + threadIdx.x; i < n4;
         i += gridDim.x * blockDim.x) {
        float4 v = reinterpret_cast<const float4*>(in)[i];
        short4v o;
        o[0] = f2bf(v.x); o[1] = f2bf(v.y); o[2] = f2bf(v.z); o[3] = f2bf(v.w);
        reinterpret_cast<short4v*>(out)[i] = o;
    }
}

// ---------------- K1: Q/K projection, hi/lo precision ----------------------
__global__ __launch_bounds__(256) void qk_mfma(
    const short* __restrict__ xh, const short* __restrict__ xl,
    const short* __restrict__ wqh, const short* __restrict__ wql, const float* __restrict__ bq,
    const short* __restrict__ wkh, const short* __restrict__ wkl, const float* __restrict__ bk,
    short* __restrict__ qhi, short* __restrict__ qlo,
    short* __restrict__ khi, short* __restrict__ klo)
{
    const int z = blockIdx.z;
    const short* wh = z ? wkh : wqh;
    const short* wl = z ? wkl : wql;
    const float* bias = z ? bk : bq;
    short* dhi = z ? khi : qhi;
    short* dlo = z ? klo : qlo;

    const int tid  = threadIdx.x;
    const int wv_  = tid >> 6, lane = tid & 63;
    const int r    = lane & 15, kg = lane >> 4;
    const int m_base = blockIdx.x * 128 + wv_ * 32;
    const int n_base = blockIdx.y * 64;

    f32x4 acc[2][4] = {};

    for (int ks = 0; ks < 32; ++ks) {
        const int k0 = ks * 32 + kg * 8;
        short8 ah0 = ld8(xh + (size_t)(m_base + r) * DIMN + k0);
        short8 al0 = ld8(xl + (size_t)(m_base + r) * DIMN + k0);
        short8 ah1 = ld8(xh + (size_t)(m_base + 16 + r) * DIMN + k0);
        short8 al1 = ld8(xl + (size_t)(m_base + 16 + r) * DIMN + k0);
        #pragma unroll
        for (int nf = 0; nf < 4; ++nf) {
            short8 bh = ld8(wh + (size_t)(n_base + nf * 16 + r) * DIMN + k0);
            short8 bl = ld8(wl + (size_t)(n_base + nf * 16 + r) * DIMN + k0);
            acc[0][nf] = MFMA(ah0, bh, acc[0][nf]);
            acc[0][nf] = MFMA(ah0, bl, acc[0][nf]);
            acc[0][nf] = MFMA(al0, bh, acc[0][nf]);
            acc[1][nf] = MFMA(ah1, bh, acc[1][nf]);
            acc[1][nf] = MFMA(ah1, bl, acc[1][nf]);
            acc[1][nf] = MFMA(al1, bh, acc[1][nf]);
        }
    }

    const int h = blockIdx.y;
    #pragma unroll
    for (int mf = 0; mf < 2; ++mf)
        #pragma unroll
        for (int nf = 0; nf < 4; ++nf)
            #pragma unroll
            for (int i = 0; i < 4; ++i) {
                const int m  = m_base + mf * 16 + kg * 4 + i;
                const int nn = n_base + nf * 16 + r;
                const float val = acc[mf][nf][i] + bias[nn];
                const int b_ = m >> 11, s = m & 2047;
                const size_t idx = (((size_t)(b_ * NH + h)) * SEQ + s) * HD + nf * 16 + r;
                const short hb = f2bf(val);
                dhi[idx] = hb;
                dlo[idx] = f2bf(val - bf2f(hb));
            }
}

// ---------------- K2: V projection (2-MFMA), transposed output -------------
__global__ __launch_bounds__(256) void v_mfma(
    const short* __restrict__ xh, const short* __restrict__ xl,
    const short* __restrict__ wvb, const float* __restrict__ bv,
    short* __restrict__ vt)
{
    const int tid  = threadIdx.x;
    const int wv_  = tid >> 6, lane = tid & 63;
    const int r    = lane & 15, kg = lane >> 4;
    const int m_base = blockIdx.x * 128 + wv_ * 32;
    const int n_base = blockIdx.y * 64;

    f32x4 acc[2][4] = {};

    for (int ks = 0; ks < 32; ++ks) {
        const int k0 = ks * 32 + kg * 8;
        short8 ah0 = ld8(xh + (size_t)(m_base + r) * DIMN + k0);
        short8 al0 = ld8(xl + (size_t)(m_base + r) * DIMN + k0);
        short8 ah1 = ld8(xh + (size_t)(m_base + 16 + r) * DIMN + k0);
        short8 al1 = ld8(xl + (size_t)(m_base + 16 + r) * DIMN + k0);
        #pragma unroll
        for (int nf = 0; nf < 4; ++nf) {
            short8 b = ld8(wvb + (size_t)(n_base + nf * 16 + r) * DIMN + k0);
            acc[0][nf] = MFMA(ah0, b, acc[0][nf]);
            acc[0][nf] = MFMA(al0, b, acc[0][nf]);
            acc[1][nf] = MFMA(ah1, b, acc[1][nf]);
            acc[1][nf] = MFMA(al1, b, acc[1][nf]);
        }
    }

    const int h = blockIdx.y;
    #pragma unroll
    for (int mf = 0; mf < 2; ++mf)
        #pragma unroll
        for (int nf = 0; nf < 4; ++nf)
            #pragma unroll
            for (int i = 0; i < 4; ++i) {
                const int m  = m_base + mf * 16 + kg * 4 + i;
                const int nn = n_base + nf * 16 + r;
                const float val = acc[mf][nf][i] + bv[nn];
                const int b_ = m >> 11, s = m & 2047;
                vt[(((size_t)(b_ * NH + h)) * HD + nf * 16 + r) * SEQ + s] = f2bf(val);
            }
}

// ---------------- K3: fused scores + exact top-k + softmax + PV ------------
__global__ __launch_bounds__(512) void fused_attn(
    const short* __restrict__ qh, const short* __restrict__ ql,
    const short* __restrict__ kh, const short* __restrict__ kl,
    const short* __restrict__ vtb, float* __restrict__ attn,
    short* __restrict__ ctxb)
{
    __shared__ float S[16][2048];   // fp32 scores, then bf16 P in-place
    __shared__ float CT[16][64];

    const int tid = threadIdx.x;
    const int w   = tid >> 6, lane = tid & 63;
    const int r   = lane & 15, kg = lane >> 4;
    const int bh  = blockIdx.y;
    const int q0  = blockIdx.x * 16;

    // ---- Phase A: S = SCALE * Q K^T, hi/lo 3-MFMA precision ----
    const size_t qoff = ((size_t)bh * SEQ + q0) * HD + r * HD + kg * 8;
    short8 a0h = ld8(qh + qoff),      a0l = ld8(ql + qoff);
    short8 a1h = ld8(qh + qoff + 32), a1l = ld8(ql + qoff + 32);
    for (int jt = w; jt < SEQ / 16; jt += 8) {
        const int j0 = jt * 16;
        const size_t koff = ((size_t)bh * SEQ + j0) * HD + r * HD + kg * 8;
        short8 b0h = ld8(kh + koff),      b0l = ld8(kl + koff);
        short8 b1h = ld8(kh + koff + 32), b1l = ld8(kl + koff + 32);
        f32x4 acc = {0.f, 0.f, 0.f, 0.f};
        acc = MFMA(a0h, b0h, acc);
        acc = MFMA(a0h, b0l, acc);
        acc = MFMA(a0l, b0h, acc);
        acc = MFMA(a1h, b1h, acc);
        acc = MFMA(a1h, b1l, acc);
        acc = MFMA(a1l, b1h, acc);
        #pragma unroll
        for (int i = 0; i < 4; ++i) S[kg * 4 + i][j0 + r] = acc[i] * SCALEF;
    }
    __syncthreads();

    // ---- Phase B: exact 32-bit radix top-k (ballot counting) + softmax ----
    // j-distribution: lane holds j = lane*4 + (jj&3) + (jj>>2)*256
    for (int rr = 0; rr < 2; ++rr) {
        const int row = w * 2 + rr;
        float vals[32]; unsigned u[32];
        const float* Srow = &S[row][0];
        #pragma unroll
        for (int g = 0; g < 8; ++g) {
            f32x4 v4 = *reinterpret_cast<const f32x4*>(Srow + lane * 4 + g * 256);
            #pragma unroll
            for (int q_ = 0; q_ < 4; ++q_) vals[g * 4 + q_] = v4[q_];
        }
        #pragma unroll
        for (int jj = 0; jj < 32; ++jj) {
            unsigned fu = __float_as_uint(vals[jj]);
            u[jj] = (fu & 0x80000000u) ? ~fu : (fu | 0x80000000u);
        }
        unsigned cur = 0;
        for (int bit = 31; bit >= 0; --bit) {
            const unsigned cand = cur | (1u << bit);
            int c = 0;
            #pragma unroll
            for (int jj = 0; jj < 32; ++jj)
                c += __popcll(__ballot(u[jj] >= cand));
            if (c >= KKEEP) cur = cand;
        }
        float m = -3.0e38f;
        #pragma unroll
        for (int jj = 0; jj < 32; ++jj) m = fmaxf(m, vals[jj]);
        #pragma unroll
        for (int off = 32; off; off >>= 1) m = fmaxf(m, __shfl_xor(m, off));
        float denom = 0.f;
        #pragma unroll
        for (int jj = 0; jj < 32; ++jj) {
            const float e = (u[jj] >= cur) ? __expf(vals[jj] - m) : 0.f;
            vals[jj] = e; denom += e;
        }
        #pragma unroll
        for (int off = 32; off; off >>= 1) denom += __shfl_xor(denom, off);
        const float inv = 1.0f / denom;

        float* arow = attn + ((size_t)bh * SEQ + q0 + row) * SEQ + lane * 4;
        char* Sb = (char*)S + row * 8192;
        const int swz = (row & 7) << 4;
        #pragma unroll
        for (int g = 0; g < 8; ++g) {
            const float p0 = vals[g * 4 + 0] * inv, p1 = vals[g * 4 + 1] * inv;
            const float p2 = vals[g * 4 + 2] * inv, p3 = vals[g * 4 + 3] * inv;
            f32x4 pv = {p0, p1, p2, p3};
            __builtin_nontemporal_store(pv, reinterpret_cast<f32x4*>(arow + g * 256));
            short4v pb;
            pb[0] = f2bf(p0); pb[1] = f2bf(p1); pb[2] = f2bf(p2); pb[3] = f2bf(p3);
            *reinterpret_cast<short4v*>(Sb + ((lane * 8 + g * 512) ^ swz)) = pb;
        }
    }
    __syncthreads();

    // ---- Phase C: ctx = P @ V (P bf16 LDS swizzled, V^T global) ----
    const int c0    = (w & 3) * 16;
    const int khalf = w >> 2;
    f32x4 acc = {0.f, 0.f, 0.f, 0.f};
    const short* vp = vtb + ((size_t)bh * HD + c0 + r) * SEQ + khalf * 1024;
    const char* Sb2 = (const char*)S;
    const int swzr = (r & 7) << 4;
    for (int ks = 0; ks < 32; ++ks) {
        const int kk = khalf * 32 + ks;
        short8 a = *reinterpret_cast<const short8*>(
            Sb2 + r * 8192 + ((kk * 64 + kg * 16) ^ swzr));
        short8 b = ld8(vp + ks * 32 + kg * 8);
        acc = MFMA(a, b, acc);
    }
    if (khalf == 1) {
        #pragma unroll
        for (int i = 0; i < 4; ++i) CT[kg * 4 + i][c0 + r] = acc[i];
    }
    __syncthreads();
    if (khalf == 0) {
        #pragma unroll
        for (int i = 0; i < 4; ++i) {
            const float val = acc[i] + CT[kg * 4 + i][c0 + r];
            ctxb[((size_t)bh * SEQ + q0 + kg * 4 + i) * HD + c0 + r] = f2bf(val);
        }
    }
}

// ---------------- K4: out = ctx @ wo^T + bo (fp32 out) ---------------------
__global__ __launch_bounds__(256) void out_mfma(
    const short* __restrict__ ctxb, const short* __restrict__ wob,
    const float* __restrict__ bo, float* __restrict__ out)
{
    const int tid = threadIdx.x;
    const int w_  = tid >> 6, lane = tid & 63;
    const int r   = lane & 15, kg = lane >> 4;
    const int m_base = blockIdx.x * 128 + w_ * 32;
    const int n_base = blockIdx.y * 64;

    f32x4 acc[2][4] = {};

    for (int ks = 0; ks < 32; ++ks) {
        const int k0 = ks * 32 + kg * 8;
        const int h = k0 >> 6, hd = k0 & 63;
        short8 a[2];
        #pragma unroll
        for (int mf = 0; mf < 2; ++mf) {
            const int m = m_base + mf * 16 + r;
            const int b_ = m >> 11, s = m & 2047;
            a[mf] = ld8(ctxb + (((size_t)(b_ * NH + h)) * SEQ + s) * HD + hd);
        }
        #pragma unroll
        for (int nf = 0; nf < 4; ++nf) {
            short8 b = ld8(wob + (size_t)(n_base + nf * 16 + r) * DIMN + k0);
            acc[0][nf] = MFMA(a[0], b, acc[0][nf]);
            acc[1][nf] = MFMA(a[1], b, acc[1][nf]);
        }
    }

    #pragma unroll
    for (int mf = 0; mf < 2; ++mf)
        #pragma unroll
        for (int nf = 0; nf < 4; ++nf)
            #pragma unroll
            for (int i = 0; i < 4; ++i) {
                const int m  = m_base + mf * 16 + kg * 4 + i;
                const int nn = n_base + nf * 16 + r;
                out[(size_t)m * DIMN + nn] = acc[mf][nf][i] + bo[nn];
            }
}

extern "C" void kernel_launch(void* const* d_in, const int* in_sizes, int n_in,
                              void* d_out, int out_size, void* d_ws, size_t ws_size,
                              hipStream_t stream) {
    const float* x  = (const float*)d_in[0];
    const float* wq = (const float*)d_in[1];
    const float* bq = (const float*)d_in[2];
    const float* wk = (const float*)d_in[3];
    const float* bk = (const float*)d_in[4];
    const float* wv = (const float*)d_in[5];
    const float* bv = (const float*)d_in[6];
    const float* wo = (const float*)d_in[7];
    const float* bo = (const float*)d_in[8];

    float* out  = (float*)d_out;
    float* attn = out + (size_t)MROWS * DIMN;   // 512 MB region, written by fused_attn

    // --- scratch that dies before fused_attn runs: lives in the attn region ---
    short* xhi = (short*)attn;
    short* xlo = xhi + (size_t)MROWS * DIMN;
    short* wqh = xlo + (size_t)MROWS * DIMN;
    short* wql = wqh + (size_t)DIMN * DIMN;
    short* wkh = wql + (size_t)DIMN * DIMN;
    short* wkl = wkh + (size_t)DIMN * DIMN;
    short* wvb = wkl + (size_t)DIMN * DIMN;

    // --- scratch that must survive into/past fused_attn: lives in d_ws ---
    const size_t QKV = (size_t)BHN * SEQ * HD;  // 4,194,304
    short* qhi = (short*)d_ws;
    short* qlo = qhi + QKV;
    short* khi = qlo + QKV;
    short* klo = khi + QKV;
    short* vt  = klo + QKV;
    short* ctx = vt  + QKV;
    short* wob = ctx + QKV;

    conv_hilo<<<1024, 256, 0, stream>>>(x,  xhi, xlo, MROWS * DIMN);
    conv_hilo<<<512,  256, 0, stream>>>(wq, wqh, wql, DIMN * DIMN);
    conv_hilo<<<512,  256, 0, stream>>>(wk, wkh, wkl, DIMN * DIMN);
    conv_bf16<<<512,  256, 0, stream>>>(wv, wvb, DIMN * DIMN);
    conv_bf16<<<512,  256, 0, stream>>>(wo, wob, DIMN * DIMN);

    qk_mfma<<<dim3(MROWS / 128, DIMN / 64, 2), 256, 0, stream>>>(
        xhi, xlo, wqh, wql, bq, wkh, wkl, bk, qhi, qlo, khi, klo);
    v_mfma<<<dim3(MROWS / 128, DIMN / 64), 256, 0, stream>>>(
        xhi, xlo, wvb, bv, vt);

    fused_attn<<<dim3(SEQ / 16, BHN), 512, 0, stream>>>(
        qhi, qlo, khi, klo, vt, attn, ctx);

    out_mfma<<<dim3(MROWS / 128, DIMN / 64), 256, 0, stream>>>(ctx, wob, bo, out);
}

// Round 5
// 1033.926 us; speedup vs baseline: 1.6183x; 1.0990x over previous
//
#include <hip/hip_runtime.h>
#include <hip/hip_bf16.h>

#define DIMN 1024
#define NH 16
#define HD 64
#define SEQ 2048
#define BATCH 2
#define BHN (BATCH*NH)        // 32
#define MROWS (BATCH*SEQ)     // 4096
#define KKEEP 409
#define SCALEF 0.125f
#define SROW 2056             // padded S row stride (floats); 8224 bytes
#define SROWB 8224

typedef __attribute__((ext_vector_type(8))) short short8;
typedef __attribute__((ext_vector_type(4))) short short4v;
typedef __attribute__((ext_vector_type(4))) float f32x4;

#define MFMA(a,b,c) __builtin_amdgcn_mfma_f32_16x16x32_bf16(a,b,c,0,0,0)

static __device__ __forceinline__ short f2bf(float f) {
    __hip_bfloat16 h = __float2bfloat16(f);
    return *reinterpret_cast<short*>(&h);
}
static __device__ __forceinline__ float bf2f(short s) {
    __hip_bfloat16 h = *reinterpret_cast<__hip_bfloat16*>(&s);
    return __bfloat162float(h);
}
static __device__ __forceinline__ short8 ld8(const short* p) {
    return *reinterpret_cast<const short8*>(p);
}

// ---------------- K0a: fp32 -> (hi, lo) bf16 pair --------------------------
__global__ void conv_hilo(const float* __restrict__ in,
                          short* __restrict__ hi, short* __restrict__ lo, int n) {
    const int n4 = n >> 2;
    for (int i = blockIdx.x * blockDim.x + threadIdx.x; i < n4;
         i += gridDim.x * blockDim.x) {
        float4 v = reinterpret_cast<const float4*>(in)[i];
        short4v h, l;
        #pragma unroll
        for (int j = 0; j < 4; ++j) {
            float f = (&v.x)[j];
            short hb = f2bf(f);
            h[j] = hb;
            l[j] = f2bf(f - bf2f(hb));
        }
        reinterpret_cast<short4v*>(hi)[i] = h;
        reinterpret_cast<short4v*>(lo)[i] = l;
    }
}

// ---------------- K0b: fp32 -> bf16 ----------------------------------------
__global__ void conv_bf16(const float* __restrict__ in, short* __restrict__ out, int n) {
    const int n4 = n >> 2;
    for (int i = blockIdx.x * blockDim.x + threadIdx.x; i < n4;
         i += gridDim.x * blockDim.x) {
        float4 v = reinterpret_cast<const float4*>(in)[i];
        short4v o;
        o[0] = f2bf(v.x); o[1] = f2bf(v.y); o[2] = f2bf(v.z); o[3] = f2bf(v.w);
        reinterpret_cast<short4v*>(out)[i] = o;
    }
}

// ---------------- K1: Q/K projection, hi/lo precision ----------------------
__global__ __launch_bounds__(256) void qk_mfma(
    const short* __restrict__ xh, const short* __restrict__ xl,
    const short* __restrict__ wqh, const short* __restrict__ wql, const float* __restrict__ bq,
    const short* __restrict__ wkh, const short* __restrict__ wkl, const float* __restrict__ bk,
    short* __restrict__ qhi, short* __restrict__ qlo,
    short* __restrict__ khi, short* __restrict__ klo)
{
    const int z = blockIdx.z;
    const short* wh = z ? wkh : wqh;
    const short* wl = z ? wkl : wql;
    const float* bias = z ? bk : bq;
    short* dhi = z ? khi : qhi;
    short* dlo = z ? klo : qlo;

    const int tid  = threadIdx.x;
    const int wv_  = tid >> 6, lane = tid & 63;
    const int r    = lane & 15, kg = lane >> 4;
    const int m_base = blockIdx.x * 128 + wv_ * 32;
    const int n_base = blockIdx.y * 64;

    f32x4 acc[2][4] = {};

    for (int ks = 0; ks < 32; ++ks) {
        const int k0 = ks * 32 + kg * 8;
        short8 ah0 = ld8(xh + (size_t)(m_base + r) * DIMN + k0);
        short8 al0 = ld8(xl + (size_t)(m_base + r) * DIMN + k0);
        short8 ah1 = ld8(xh + (size_t)(m_base + 16 + r) * DIMN + k0);
        short8 al1 = ld8(xl + (size_t)(m_base + 16 + r) * DIMN + k0);
        #pragma unroll
        for (int nf = 0; nf < 4; ++nf) {
            short8 bh = ld8(wh + (size_t)(n_base + nf * 16 + r) * DIMN + k0);
            short8 bl = ld8(wl + (size_t)(n_base + nf * 16 + r) * DIMN + k0);
            acc[0][nf] = MFMA(ah0, bh, acc[0][nf]);
            acc[0][nf] = MFMA(ah0, bl, acc[0][nf]);
            acc[0][nf] = MFMA(al0, bh, acc[0][nf]);
            acc[1][nf] = MFMA(ah1, bh, acc[1][nf]);
            acc[1][nf] = MFMA(ah1, bl, acc[1][nf]);
            acc[1][nf] = MFMA(al1, bh, acc[1][nf]);
        }
    }

    const int h = blockIdx.y;
    #pragma unroll
    for (int mf = 0; mf < 2; ++mf)
        #pragma unroll
        for (int nf = 0; nf < 4; ++nf)
            #pragma unroll
            for (int i = 0; i < 4; ++i) {
                const int m  = m_base + mf * 16 + kg * 4 + i;
                const int nn = n_base + nf * 16 + r;
                const float val = acc[mf][nf][i] + bias[nn];
                const int b_ = m >> 11, s = m & 2047;
                const size_t idx = (((size_t)(b_ * NH + h)) * SEQ + s) * HD + nf * 16 + r;
                const short hb = f2bf(val);
                dhi[idx] = hb;
                dlo[idx] = f2bf(val - bf2f(hb));
            }
}

// ---------------- K2: V projection (2-MFMA), transposed output -------------
__global__ __launch_bounds__(256) void v_mfma(
    const short* __restrict__ xh, const short* __restrict__ xl,
    const short* __restrict__ wvb, const float* __restrict__ bv,
    short* __restrict__ vt)
{
    const int tid  = threadIdx.x;
    const int wv_  = tid >> 6, lane = tid & 63;
    const int r    = lane & 15, kg = lane >> 4;
    const int m_base = blockIdx.x * 128 + wv_ * 32;
    const int n_base = blockIdx.y * 64;

    f32x4 acc[2][4] = {};

    for (int ks = 0; ks < 32; ++ks) {
        const int k0 = ks * 32 + kg * 8;
        short8 ah0 = ld8(xh + (size_t)(m_base + r) * DIMN + k0);
        short8 al0 = ld8(xl + (size_t)(m_base + r) * DIMN + k0);
        short8 ah1 = ld8(xh + (size_t)(m_base + 16 + r) * DIMN + k0);
        short8 al1 = ld8(xl + (size_t)(m_base + 16 + r) * DIMN + k0);
        #pragma unroll
        for (int nf = 0; nf < 4; ++nf) {
            short8 b = ld8(wvb + (size_t)(n_base + nf * 16 + r) * DIMN + k0);
            acc[0][nf] = MFMA(ah0, b, acc[0][nf]);
            acc[0][nf] = MFMA(al0, b, acc[0][nf]);
            acc[1][nf] = MFMA(ah1, b, acc[1][nf]);
            acc[1][nf] = MFMA(al1, b, acc[1][nf]);
        }
    }

    const int h = blockIdx.y;
    #pragma unroll
    for (int mf = 0; mf < 2; ++mf)
        #pragma unroll
        for (int nf = 0; nf < 4; ++nf)
            #pragma unroll
            for (int i = 0; i < 4; ++i) {
                const int m  = m_base + mf * 16 + kg * 4 + i;
                const int nn = n_base + nf * 16 + r;
                const float val = acc[mf][nf][i] + bv[nn];
                const int b_ = m >> 11, s = m & 2047;
                vt[(((size_t)(b_ * NH + h)) * HD + nf * 16 + r) * SEQ + s] = f2bf(val);
            }
}

// ---------------- K3: fused scores + exact top-k + softmax + PV ------------
// 1024 threads = 16 waves; 16 q-rows per block; 4 waves/SIMD occupancy.
__global__ __launch_bounds__(1024, 4) void fused_attn(
    const short* __restrict__ qh, const short* __restrict__ ql,
    const short* __restrict__ kh, const short* __restrict__ kl,
    const short* __restrict__ vtb, float* __restrict__ attn,
    short* __restrict__ ctxb)
{
    __shared__ float S[16][SROW];     // 131.6 KB, padded rows (bank-spread)
    __shared__ float CT[3][16][64];   // 12 KB partial ctx from k-quarters 1..3

    const int tid = threadIdx.x;
    const int w   = tid >> 6, lane = tid & 63;
    const int r   = lane & 15, kg = lane >> 4;
    const int bh  = blockIdx.y;
    const int q0  = blockIdx.x * 16;

    // ---- Phase A: S = SCALE * Q K^T, hi/lo 3-MFMA precision ----
    const size_t qoff = ((size_t)bh * SEQ + q0) * HD + r * HD + kg * 8;
    short8 a0h = ld8(qh + qoff),      a0l = ld8(ql + qoff);
    short8 a1h = ld8(qh + qoff + 32), a1l = ld8(ql + qoff + 32);
    for (int jt = w; jt < SEQ / 16; jt += 16) {
        const int j0 = jt * 16;
        const size_t koff = ((size_t)bh * SEQ + j0) * HD + r * HD + kg * 8;
        short8 b0h = ld8(kh + koff),      b0l = ld8(kl + koff);
        short8 b1h = ld8(kh + koff + 32), b1l = ld8(kl + koff + 32);
        f32x4 accA = {0.f, 0.f, 0.f, 0.f};     // two independent 3-chains
        f32x4 accB = {0.f, 0.f, 0.f, 0.f};
        accA = MFMA(a0h, b0h, accA);
        accB = MFMA(a1h, b1h, accB);
        accA = MFMA(a0h, b0l, accA);
        accB = MFMA(a1h, b1l, accB);
        accA = MFMA(a0l, b0h, accA);
        accB = MFMA(a1l, b1h, accB);
        #pragma unroll
        for (int i = 0; i < 4; ++i)
            S[kg * 4 + i][j0 + r] = (accA[i] + accB[i]) * SCALEF;
    }
    __syncthreads();

    // ---- Phase B: exact 32-bit radix top-k (ballot counting) + softmax ----
    // one row per wave; lane holds j = lane*4 + (jj&3) + (jj>>2)*256
    {
        const int row = w;
        float vals[32]; unsigned u[32];
        const float* Srow = &S[row][0];
        #pragma unroll
        for (int g = 0; g < 8; ++g) {
            f32x4 v4 = *reinterpret_cast<const f32x4*>(Srow + lane * 4 + g * 256);
            #pragma unroll
            for (int q_ = 0; q_ < 4; ++q_) vals[g * 4 + q_] = v4[q_];
        }
        #pragma unroll
        for (int jj = 0; jj < 32; ++jj) {
            unsigned fu = __float_as_uint(vals[jj]);
            u[jj] = (fu & 0x80000000u) ? ~fu : (fu | 0x80000000u);
        }
        unsigned cur = 0;
        for (int bit = 31; bit >= 0; --bit) {
            const unsigned cand = cur | (1u << bit);
            int c = 0;
            #pragma unroll
            for (int jj = 0; jj < 32; ++jj)
                c += __popcll(__ballot(u[jj] >= cand));
            if (c >= KKEEP) cur = cand;
        }
        float m = -3.0e38f;
        #pragma unroll
        for (int jj = 0; jj < 32; ++jj) m = fmaxf(m, vals[jj]);
        #pragma unroll
        for (int off = 32; off; off >>= 1) m = fmaxf(m, __shfl_xor(m, off));
        float denom = 0.f;
        #pragma unroll
        for (int jj = 0; jj < 32; ++jj) {
            const float e = (u[jj] >= cur) ? __expf(vals[jj] - m) : 0.f;
            vals[jj] = e; denom += e;
        }
        #pragma unroll
        for (int off = 32; off; off >>= 1) denom += __shfl_xor(denom, off);
        const float inv = 1.0f / denom;

        float* arow = attn + ((size_t)bh * SEQ + q0 + row) * SEQ + lane * 4;
        char* Sb = (char*)&S[row][0];
        const int swz = (row & 7) << 4;
        #pragma unroll
        for (int g = 0; g < 8; ++g) {
            const float p0 = vals[g * 4 + 0] * inv, p1 = vals[g * 4 + 1] * inv;
            const float p2 = vals[g * 4 + 2] * inv, p3 = vals[g * 4 + 3] * inv;
            f32x4 pv = {p0, p1, p2, p3};
            __builtin_nontemporal_store(pv, reinterpret_cast<f32x4*>(arow + g * 256));
            short4v pb;
            pb[0] = f2bf(p0); pb[1] = f2bf(p1); pb[2] = f2bf(p2); pb[3] = f2bf(p3);
            *reinterpret_cast<short4v*>(Sb + ((lane * 8 + g * 512) ^ swz)) = pb;
        }
    }
    __syncthreads();

    // ---- Phase C: ctx = P @ V; 16 waves = 4 col-groups x 4 k-quarters ----
    const int c0 = (w & 3) * 16;
    const int kq = w >> 2;
    f32x4 acc0 = {0.f, 0.f, 0.f, 0.f};
    f32x4 acc1 = {0.f, 0.f, 0.f, 0.f};
    const short* vp = vtb + ((size_t)bh * HD + c0 + r) * SEQ + kq * 512;
    const int swzr = (r & 7) << 4;
    const char* SrowB = (const char*)&S[r][0];
    for (int ks = 0; ks < 16; ks += 2) {
        const int kk0 = kq * 16 + ks, kk1 = kk0 + 1;
        short8 pa0 = *reinterpret_cast<const short8*>(
            SrowB + ((kk0 * 64 + kg * 16) ^ swzr));
        short8 pa1 = *reinterpret_cast<const short8*>(
            SrowB + ((kk1 * 64 + kg * 16) ^ swzr));
        short8 vb0 = ld8(vp + ks * 32 + kg * 8);
        short8 vb1 = ld8(vp + ks * 32 + 32 + kg * 8);
        acc0 = MFMA(pa0, vb0, acc0);
        acc1 = MFMA(pa1, vb1, acc1);
    }
    acc0[0] += acc1[0]; acc0[1] += acc1[1];
    acc0[2] += acc1[2]; acc0[3] += acc1[3];
    if (kq != 0) {
        #pragma unroll
        for (int i = 0; i < 4; ++i) CT[kq - 1][kg * 4 + i][c0 + r] = acc0[i];
    }
    __syncthreads();
    if (kq == 0) {
        #pragma unroll
        for (int i = 0; i < 4; ++i) {
            const float val = acc0[i] + CT[0][kg * 4 + i][c0 + r]
                            + CT[1][kg * 4 + i][c0 + r] + CT[2][kg * 4 + i][c0 + r];
            ctxb[((size_t)bh * SEQ + q0 + kg * 4 + i) * HD + c0 + r] = f2bf(val);
        }
    }
}

// ---------------- K4: out = ctx @ wo^T + bo (fp32 out) ---------------------
__global__ __launch_bounds__(256) void out_mfma(
    const short* __restrict__ ctxb, const short* __restrict__ wob,
    const float* __restrict__ bo, float* __restrict__ out)
{
    const int tid = threadIdx.x;
    const int w_  = tid >> 6, lane = tid & 63;
    const int r   = lane & 15, kg = lane >> 4;
    const int m_base = blockIdx.x * 128 + w_ * 32;
    const int n_base = blockIdx.y * 64;

    f32x4 acc[2][4] = {};

    for (int ks = 0; ks < 32; ++ks) {
        const int k0 = ks * 32 + kg * 8;
        const int h = k0 >> 6, hd = k0 & 63;
        short8 a[2];
        #pragma unroll
        for (int mf = 0; mf < 2; ++mf) {
            const int m = m_base + mf * 16 + r;
            const int b_ = m >> 11, s = m & 2047;
            a[mf] = ld8(ctxb + (((size_t)(b_ * NH + h)) * SEQ + s) * HD + hd);
        }
        #pragma unroll
        for (int nf = 0; nf < 4; ++nf) {
            short8 b = ld8(wob + (size_t)(n_base + nf * 16 + r) * DIMN + k0);
            acc[0][nf] = MFMA(a[0], b, acc[0][nf]);
            acc[1][nf] = MFMA(a[1], b, acc[1][nf]);
        }
    }

    #pragma unroll
    for (int mf = 0; mf < 2; ++mf)
        #pragma unroll
        for (int nf = 0; nf < 4; ++nf)
            #pragma unroll
            for (int i = 0; i < 4; ++i) {
                const int m  = m_base + mf * 16 + kg * 4 + i;
                const int nn = n_base + nf * 16 + r;
                out[(size_t)m * DIMN + nn] = acc[mf][nf][i] + bo[nn];
            }
}

extern "C" void kernel_launch(void* const* d_in, const int* in_sizes, int n_in,
                              void* d_out, int out_size, void* d_ws, size_t ws_size,
                              hipStream_t stream) {
    const float* x  = (const float*)d_in[0];
    const float* wq = (const float*)d_in[1];
    const float* bq = (const float*)d_in[2];
    const float* wk = (const float*)d_in[3];
    const float* bk = (const float*)d_in[4];
    const float* wv = (const float*)d_in[5];
    const float* bv = (const float*)d_in[6];
    const float* wo = (const float*)d_in[7];
    const float* bo = (const float*)d_in[8];

    float* out  = (float*)d_out;
    float* attn = out + (size_t)MROWS * DIMN;   // 512 MB region, written by fused_attn

    // --- scratch that dies before fused_attn runs: lives in the attn region ---
    short* xhi = (short*)attn;
    short* xlo = xhi + (size_t)MROWS * DIMN;
    short* wqh = xlo + (size_t)MROWS * DIMN;
    short* wql = wqh + (size_t)DIMN * DIMN;
    short* wkh = wql + (size_t)DIMN * DIMN;
    short* wkl = wkh + (size_t)DIMN * DIMN;
    short* wvb = wkl + (size_t)DIMN * DIMN;

    // --- scratch that must survive into/past fused_attn: lives in d_ws ---
    const size_t QKV = (size_t)BHN * SEQ * HD;  // 4,194,304
    short* qhi = (short*)d_ws;
    short* qlo = qhi + QKV;
    short* khi = qlo + QKV;
    short* klo = khi + QKV;
    short* vt  = klo + QKV;
    short* ctx = vt  + QKV;
    short* wob = ctx + QKV;

    conv_hilo<<<1024, 256, 0, stream>>>(x,  xhi, xlo, MROWS * DIMN);
    conv_hilo<<<512,  256, 0, stream>>>(wq, wqh, wql, DIMN * DIMN);
    conv_hilo<<<512,  256, 0, stream>>>(wk, wkh, wkl, DIMN * DIMN);
    conv_bf16<<<512,  256, 0, stream>>>(wv, wvb, DIMN * DIMN);
    conv_bf16<<<512,  256, 0, stream>>>(wo, wob, DIMN * DIMN);

    qk_mfma<<<dim3(MROWS / 128, DIMN / 64, 2), 256, 0, stream>>>(
        xhi, xlo, wqh, wql, bq, wkh, wkl, bk, qhi, qlo, khi, klo);
    v_mfma<<<dim3(MROWS / 128, DIMN / 64), 256, 0, stream>>>(
        xhi, xlo, wvb, bv, vt);

    fused_attn<<<dim3(SEQ / 16, BHN), 1024, 0, stream>>>(
        qhi, qlo, khi, klo, vt, attn, ctx);

    out_mfma<<<dim3(MROWS / 128, DIMN / 64), 256, 0, stream>>>(ctx, wob, bo, out);
}